// Round 7
// baseline (215.656 us; speedup 1.0000x reference)
//
#include <hip/hip_runtime.h>
#include <hip/hip_fp16.h>
#include <math.h>

// ---- problem constants (match reference) ----
#define NCOLS   407
#define RAD_OFF 87
#define ANG_OFF 151

// shiftR[r] = 0.8 + r*0.275  (r=0..15)
// shiftA[a] = 0.8 + a*0.675  (a=0..3)
// shiftZ[z] = pi/8 + z*pi/4  (z=0..3)

typedef __attribute__((ext_vector_type(8))) _Float16 f16x8;
typedef __attribute__((ext_vector_type(4))) float    f32x4;

static __device__ inline unsigned pack2(float a, float b) {
    __half2 h = __floats2half2_rn(a, b);
    return *reinterpret_cast<unsigned*>(&h);
}
static __device__ inline float2 unpack2(unsigned u) {
    __half2 h = *reinterpret_cast<__half2*>(&u);
    return __half22float2(h);
}

// ============ init: zero counts + per-atom valence table ============
__global__ __launch_bounds__(256) void init_kernel(const int* __restrict__ species,
                                                   const float4* __restrict__ valence,
                                                   float4* __restrict__ val_atom,
                                                   int* __restrict__ counts,
                                                   int n_atoms) {
    int idx = blockIdx.x * 256 + threadIdx.x;
    if (idx < 2 * n_atoms) counts[idx] = 0;
    if (idx < n_atoms) val_atom[idx] = valence[species[idx]];
}

// ============ histograms + packed per-angular-edge record ============
// edata[e] = { f32 d, f32 sw, half2 v01, half2 v23 }  (16B)
__global__ __launch_bounds__(256) void hist_edata_kernel(const int* __restrict__ esrc,
                                                         const int* __restrict__ central,
                                                         const float* __restrict__ ang_dist,
                                                         const float* __restrict__ ang_sw,
                                                         const int* __restrict__ ang_edge_dst,
                                                         const float4* __restrict__ val_atom,
                                                         int* __restrict__ rad_counts,
                                                         int* __restrict__ ang_counts,
                                                         uint4* __restrict__ edata,
                                                         int n_edges, int n_pairs, int n_ang_edges) {
    int i = blockIdx.x * 256 + threadIdx.x;
    if (i < n_edges) {
        atomicAdd(&rad_counts[esrc[i]], 1);
    } else {
        int p = i - n_edges;
        if (p < n_pairs) atomicAdd(&ang_counts[central[p]], 1);
    }
    if (i < n_ang_edges) {
        float4 v = val_atom[ang_edge_dst[i]];
        uint4 r;
        r.x = __float_as_uint(ang_dist[i]);
        r.y = __float_as_uint(ang_sw[i]);
        r.z = pack2(v.x, v.y);
        r.w = pack2(v.z, v.w);
        edata[i] = r;
    }
}

// ============ fused scan: block 0 = radial, block 1 = angular ============
// counts[] is overwritten in-place with the exclusive prefix (serves as cursor)
__global__ __launch_bounds__(1024) void scan_kernel(int* __restrict__ rad_counts,
                                                    int* __restrict__ ang_counts,
                                                    int* __restrict__ rad_offsets,
                                                    int* __restrict__ ang_offsets,
                                                    int n) {
    int* counts  = (blockIdx.x == 0) ? rad_counts  : ang_counts;
    int* offsets = (blockIdx.x == 0) ? rad_offsets : ang_offsets;
    __shared__ int part[1024];
    int t = threadIdx.x;
    int C = (n + 1023) >> 10;
    int lo = min(t * C, n);
    int hi = min(lo + C, n);
    int s = 0;
    for (int i = lo; i < hi; ++i) s += counts[i];
    part[t] = s;
    __syncthreads();
    for (int off = 1; off < 1024; off <<= 1) {
        int v = (t >= off) ? part[t - off] : 0;
        __syncthreads();
        part[t] += v;
        __syncthreads();
    }
    int run = part[t] - s;   // exclusive base for this thread's range
    for (int i = lo; i < hi; ++i) {
        int c = counts[i];
        offsets[i] = run;
        counts[i]  = run;    // cursor
        run += c;
    }
    if (t == 1023) offsets[n] = part[1023];
}

// ============ scatter: radial 16B payload to slot; angular 4B perm to slot ============
__global__ __launch_bounds__(256) void scatter_kernel(
    const float* __restrict__ dist, const float* __restrict__ sw,
    const int* __restrict__ esrc, const int* __restrict__ edst,
    const int* __restrict__ central,
    const float4* __restrict__ val_atom,
    int* __restrict__ rad_cursor, int* __restrict__ ang_cursor,
    uint4* __restrict__ rad_pay, int* __restrict__ ang_perm,
    int n_edges, int n_pairs, int nb_rad)
{
    int bid = blockIdx.x;
    int t = threadIdx.x;
    if (bid < nb_rad) {
        int i = bid * 256 + t;
        if (i >= n_edges) return;
        float d  = dist[i];
        float ps = 0.25f * sw[i];
        float4 v = val_atom[edst[i]];
        uint4 rec;
        rec.x = __float_as_uint(d);
        rec.y = pack2(ps * v.x, ps * v.y);
        rec.z = pack2(ps * v.z, ps * v.w);
        rec.w = 0u;
        int slot = atomicAdd(&rad_cursor[esrc[i]], 1);
        rad_pay[slot] = rec;
    } else {
        int p = (bid - nb_rad) * 256 + t;
        if (p >= n_pairs) return;
        int slot = atomicAdd(&ang_cursor[central[p]], 1);
        ang_perm[slot] = p;
    }
}

// ============ phase B: one wave per atom ============
// waves [0, n_atoms): angular — gather pair data, compute w/u fp16, MFMA 16x16xK
// waves [n_atoms, 2n): radial broadcast-gather + onehot
__global__ __launch_bounds__(256) void phaseB_kernel(
    const int* __restrict__ ang_perm, const int* __restrict__ ang_offsets,
    const float* __restrict__ ang_angles,
    const int* __restrict__ psrc, const int* __restrict__ pdst,
    const uint4* __restrict__ edata,
    const uint4* __restrict__ rad_pay, const int* __restrict__ rad_offsets,
    const int* __restrict__ species,
    float* __restrict__ out, int n_atoms)
{
    __shared__ uint4 sh[4][256];      // 4KB per wave, wave-private
    int wid  = (blockIdx.x << 2) + (threadIdx.x >> 6);
    int lane = threadIdx.x & 63;
    uint4* my = sh[threadIdx.x >> 6];

    if (wid < n_atoms) {
        // ---------------- angular (MFMA) ----------------
        int atom = wid;
        int beg = ang_offsets[atom];
        int end = ang_offsets[atom + 1];
        int m  = lane & 15;          // MFMA row (az) for A / col (ij) for B
        int g4 = lane >> 4;          // k-group
        const _Float16* hl = (const _Float16*)my;   // pair-major: 32 halves/pair
        f32x4 acc = {0.f, 0.f, 0.f, 0.f};

        for (int base = beg; base < end; base += 64) {
            int idx = base + lane;
            unsigned q[16];
            if (idx < end) {
                int p  = ang_perm[idx];             // coalesced
                int e1 = psrc[p];
                int e2 = pdst[p];
                float ang = ang_angles[p];
                uint4 r1 = edata[e1];
                uint4 r2 = edata[e2];
                float d12 = 0.5f * (__uint_as_float(r1.x) + __uint_as_float(r2.x));
                float swp = 2.0f * __uint_as_float(r1.y) * __uint_as_float(r2.y);
                float2 v1a = unpack2(r1.z), v1b = unpack2(r1.w);
                float2 v2a = unpack2(r2.z), v2b = unpack2(r2.w);
                float vp[4] = {v1a.x + v2a.x, v1a.y + v2a.y, v1b.x + v2b.x, v1b.y + v2b.y};
                float vm[4] = {v1a.x * v2a.x, v1a.y * v2a.y, v1b.x * v2b.x, v1b.y * v2b.y};

                float sa, ca;
                __sincosf(ang, &sa, &ca);
                const float czv[4] = { 0.92387953f,  0.38268343f, -0.38268343f, -0.92387953f };
                const float szv[4] = { 0.38268343f,  0.92387953f,  0.92387953f,  0.38268343f };
                float f1v[4];
                #pragma unroll
                for (int z = 0; z < 4; ++z) {
                    float y = 0.5f + 0.5f * (ca * czv[z] + sa * szv[z]);
                    float y2 = y * y, y4 = y2 * y2, y8 = y4 * y4, y16 = y8 * y8;
                    f1v[z] = y16 * y16;             // y^32
                }
                float f2sv[4];
                #pragma unroll
                for (int a = 0; a < 4; ++a) {
                    float x = d12 - (0.8f + 0.675f * (float)a);
                    f2sv[a] = swp * __expf(-8.0f * x * x);
                }
                #pragma unroll
                for (int a = 0; a < 4; ++a) {       // w[az] = f2s[a]*f1[z]
                    q[a * 2 + 0] = pack2(f2sv[a] * f1v[0], f2sv[a] * f1v[1]);
                    q[a * 2 + 1] = pack2(f2sv[a] * f1v[2], f2sv[a] * f1v[3]);
                }
                #pragma unroll
                for (int i2 = 0; i2 < 4; ++i2) {    // u[ij] = vp[i]*vm[j]
                    q[8 + i2 * 2 + 0] = pack2(vp[i2] * vm[0], vp[i2] * vm[1]);
                    q[8 + i2 * 2 + 1] = pack2(vp[i2] * vm[2], vp[i2] * vm[3]);
                }
            } else {
                #pragma unroll
                for (int k = 0; k < 16; ++k) q[k] = 0u;   // zero-pad tail pairs
            }
            // stage pair record: [w0..15 | u0..15] halves at 64B stride
            my[lane * 4 + 0] = make_uint4(q[0],  q[1],  q[2],  q[3]);
            my[lane * 4 + 1] = make_uint4(q[4],  q[5],  q[6],  q[7]);
            my[lane * 4 + 2] = make_uint4(q[8],  q[9],  q[10], q[11]);
            my[lane * 4 + 3] = make_uint4(q[12], q[13], q[14], q[15]);
            asm volatile("s_waitcnt lgkmcnt(0)" ::: "memory");

            int cnt = min(64, end - base);
            {
                f16x8 wf, uf;
                #pragma unroll
                for (int i = 0; i < 8; ++i) {
                    int row = (g4 << 3) + i;        // pairs 0..31
                    wf[i] = hl[row * 32 + m];
                    uf[i] = hl[row * 32 + 16 + m];
                }
                acc = __builtin_amdgcn_mfma_f32_16x16x32_f16(wf, uf, acc, 0, 0, 0);
            }
            if (cnt > 32) {
                f16x8 wf, uf;
                #pragma unroll
                for (int i = 0; i < 8; ++i) {
                    int row = 32 + (g4 << 3) + i;   // pairs 32..63
                    wf[i] = hl[row * 32 + m];
                    uf[i] = hl[row * 32 + 16 + m];
                }
                acc = __builtin_amdgcn_mfma_f32_16x16x32_f16(wf, uf, acc, 0, 0, 0);
            }
            asm volatile("s_waitcnt lgkmcnt(0)" ::: "memory");
        }
        // C/D layout (m89-verified): col = lane&15, row = (lane>>4)*4 + reg
        float* orow = out + (size_t)atom * NCOLS + ANG_OFF;
        #pragma unroll
        for (int r = 0; r < 4; ++r)
            orow[(g4 * 4 + r) * 16 + m] = acc[r];
        return;
    }

    // ---------------- radial + onehot ----------------
    int atom = wid - n_atoms;
    if (atom >= n_atoms) return;
    int beg = rad_offsets[atom];
    int end = rad_offsets[atom + 1];
    int r = lane >> 2, k = lane & 3;
    float shift = 0.8f + 0.275f * (float)r;
    float acc = 0.0f;
    for (int base = beg; base < end; base += 64) {
        int idx = base + lane;
        if (idx < end) my[lane] = rad_pay[idx];     // coalesced 16B
        asm volatile("s_waitcnt lgkmcnt(0)" ::: "memory");
        int cnt = min(64, end - base);
        for (int e = 0; e < cnt; ++e) {
            uint4 rec = my[e];                      // broadcast b128
            float d = __uint_as_float(rec.x);
            float2 f01 = unpack2(rec.y);
            float2 f23 = unpack2(rec.z);
            float pv = (k == 0) ? f01.x : (k == 1) ? f01.y : (k == 2) ? f23.x : f23.y;
            float x = d - shift;
            acc += __expf(-16.0f * x * x) * pv;
        }
        asm volatile("s_waitcnt lgkmcnt(0)" ::: "memory");
    }
    size_t rowbase = (size_t)atom * NCOLS;
    out[rowbase + RAD_OFF + lane] = acc;
    int sp = species[atom];
    out[rowbase + lane] = (lane == sp) ? 1.0f : 0.0f;
    if (lane < 23) out[rowbase + 64 + lane] = ((64 + lane) == sp) ? 1.0f : 0.0f;
}

extern "C" void kernel_launch(void* const* d_in, const int* in_sizes, int n_in,
                              void* d_out, int out_size, void* d_ws, size_t ws_size,
                              hipStream_t stream) {
    const int*   species      = (const int*)  d_in[0];
    const float* distances    = (const float*)d_in[1];
    const float* switch_      = (const float*)d_in[2];
    const int*   edge_src     = (const int*)  d_in[3];
    const int*   edge_dst     = (const int*)  d_in[4];
    const float* ang_angles   = (const float*)d_in[5];
    const float* ang_dist     = (const float*)d_in[6];
    const float* ang_switch   = (const float*)d_in[7];
    const int*   ang_edge_dst = (const int*)  d_in[8];
    const int*   angle_src    = (const int*)  d_in[9];
    const int*   angle_dst    = (const int*)  d_in[10];
    const int*   central_atom = (const int*)  d_in[11];
    const float4* valence     = (const float4*)d_in[12];

    float* out = (float*)d_out;

    const int n_atoms     = in_sizes[0];
    const int n_edges     = in_sizes[1];
    const int n_ang_edges = in_sizes[6];
    const int n_pairs     = in_sizes[5];

    // ---- workspace layout (16B-aligned), total ~= 15.6 MB ----
    char* ws = (char*)d_ws;
    size_t off = 0;
    auto alloc = [&](size_t bytes) -> void* {
        void* p = ws + off;
        off = (off + bytes + 15) & ~(size_t)15;
        return p;
    };
    uint4*  rad_pay     = (uint4*) alloc((size_t)n_edges * 16);                 // 10.24 MB
    uint4*  edata       = (uint4*) alloc((size_t)n_ang_edges * 16);             //  2.56 MB
    int*    ang_perm    = (int*)   alloc((size_t)n_pairs * sizeof(int));        //  2.24 MB
    float4* val_atom    = (float4*)alloc((size_t)n_atoms * sizeof(float4));     //  0.32 MB
    int*    counts      = (int*)   alloc((size_t)2 * n_atoms * sizeof(int));    //  0.16 MB
    int*    rad_offsets = (int*)   alloc((size_t)(n_atoms + 1) * sizeof(int));
    int*    ang_offsets = (int*)   alloc((size_t)(n_atoms + 1) * sizeof(int));
    int* rad_counts = counts;            // doubles as cursor after scan
    int* ang_counts = counts + n_atoms;  // doubles as cursor after scan

    init_kernel<<<(2 * n_atoms + 255) / 256, 256, 0, stream>>>(
        species, valence, val_atom, counts, n_atoms);

    int n_work = n_edges + n_pairs;
    hist_edata_kernel<<<(n_work + 255) / 256, 256, 0, stream>>>(
        edge_src, central_atom, ang_dist, ang_switch, ang_edge_dst, val_atom,
        rad_counts, ang_counts, edata, n_edges, n_pairs, n_ang_edges);

    scan_kernel<<<2, 1024, 0, stream>>>(rad_counts, ang_counts, rad_offsets, ang_offsets, n_atoms);

    int nb_rad = (n_edges + 255) / 256;
    int nb_ang = (n_pairs + 255) / 256;
    scatter_kernel<<<nb_rad + nb_ang, 256, 0, stream>>>(
        distances, switch_, edge_src, edge_dst, central_atom,
        val_atom, rad_counts, ang_counts,
        rad_pay, ang_perm, n_edges, n_pairs, nb_rad);

    int nb_B = (2 * n_atoms + 3) / 4;    // 4 waves/block, 1 atom per wave
    phaseB_kernel<<<nb_B, 256, 0, stream>>>(
        ang_perm, ang_offsets, ang_angles, angle_src, angle_dst, edata,
        rad_pay, rad_offsets, species, out, n_atoms);
}

// Round 8
// 142.418 us; speedup vs baseline: 1.5142x; 1.5142x over previous
//
#include <hip/hip_runtime.h>
#include <hip/hip_fp16.h>
#include <math.h>

// ---- problem constants (match reference) ----
#define NCOLS   407
#define RAD_OFF 87
#define ANG_OFF 151

// shiftR[r] = 0.8 + r*0.275  (r=0..15)
// shiftA[a] = 0.8 + a*0.675  (a=0..3)
// shiftZ[z] = pi/8 + z*pi/4  (z=0..3)

typedef __attribute__((ext_vector_type(8))) _Float16 f16x8;
typedef __attribute__((ext_vector_type(4))) float    f32x4;

static __device__ inline unsigned pack2(float a, float b) {
    __half2 h = __floats2half2_rn(a, b);
    return *reinterpret_cast<unsigned*>(&h);
}
static __device__ inline float2 unpack2(unsigned u) {
    __half2 h = *reinterpret_cast<__half2*>(&u);
    return __half22float2(h);
}

// ============ init: zero counts + per-atom valence table ============
__global__ __launch_bounds__(256) void init_kernel(const int* __restrict__ species,
                                                   const float4* __restrict__ valence,
                                                   float4* __restrict__ val_atom,
                                                   int* __restrict__ counts,
                                                   int n_atoms) {
    int idx = blockIdx.x * 256 + threadIdx.x;
    if (idx < 2 * n_atoms) counts[idx] = 0;
    if (idx < n_atoms) val_atom[idx] = valence[species[idx]];
}

// ============ hist (returned -> rank) + packed per-angular-edge record ============
// edata[e] = { f32 d, f32 sw, half2 v01, half2 v23 }  (16B)
__global__ __launch_bounds__(256) void hist_kernel(const int* __restrict__ esrc,
                                                   const int* __restrict__ central,
                                                   const float* __restrict__ ang_dist,
                                                   const float* __restrict__ ang_sw,
                                                   const int* __restrict__ ang_edge_dst,
                                                   const float4* __restrict__ val_atom,
                                                   int* __restrict__ rad_counts,
                                                   int* __restrict__ ang_counts,
                                                   int* __restrict__ rank_rad,
                                                   int* __restrict__ rank_ang,
                                                   uint4* __restrict__ edata,
                                                   int n_edges, int n_pairs, int n_ang_edges) {
    int i = blockIdx.x * 256 + threadIdx.x;
    if (i < n_edges) {
        rank_rad[i] = atomicAdd(&rad_counts[esrc[i]], 1);   // coalesced rank write
    } else {
        int p = i - n_edges;
        if (p < n_pairs) rank_ang[p] = atomicAdd(&ang_counts[central[p]], 1);
    }
    if (i < n_ang_edges) {
        float4 v = val_atom[ang_edge_dst[i]];
        uint4 r;
        r.x = __float_as_uint(ang_dist[i]);
        r.y = __float_as_uint(ang_sw[i]);
        r.z = pack2(v.x, v.y);
        r.w = pack2(v.z, v.w);
        edata[i] = r;
    }
}

// ============ fused scan: block 0 = radial, block 1 = angular ============
__global__ __launch_bounds__(1024) void scan_kernel(int* __restrict__ rad_counts,
                                                    int* __restrict__ ang_counts,
                                                    int* __restrict__ rad_offsets,
                                                    int* __restrict__ ang_offsets,
                                                    int n) {
    int* counts  = (blockIdx.x == 0) ? rad_counts  : ang_counts;
    int* offsets = (blockIdx.x == 0) ? rad_offsets : ang_offsets;
    __shared__ int part[1024];
    int t = threadIdx.x;
    int C = (n + 1023) >> 10;
    int lo = min(t * C, n);
    int hi = min(lo + C, n);
    int s = 0;
    for (int i = lo; i < hi; ++i) s += counts[i];
    part[t] = s;
    __syncthreads();
    for (int off = 1; off < 1024; off <<= 1) {
        int v = (t >= off) ? part[t - off] : 0;
        __syncthreads();
        part[t] += v;
        __syncthreads();
    }
    int run = part[t] - s;   // exclusive base for this thread's range
    for (int i = lo; i < hi; ++i) {
        int c = counts[i];
        offsets[i] = run;
        run += c;
    }
    if (t == 1023) offsets[n] = part[1023];
}

// ============ scatter (NO atomics): slot = offsets[atom] + rank ============
// radial : 16B record {d, pv01, pv23, 0} to slot
// angular: 16B record {e1, e2, angle_bits, 0} to slot
__global__ __launch_bounds__(256) void scatter_kernel(
    const float* __restrict__ dist, const float* __restrict__ sw,
    const int* __restrict__ esrc, const int* __restrict__ edst,
    const float* __restrict__ ang_angles,
    const int* __restrict__ psrc, const int* __restrict__ pdst,
    const int* __restrict__ central,
    const float4* __restrict__ val_atom,
    const int* __restrict__ rad_offsets, const int* __restrict__ ang_offsets,
    const int* __restrict__ rank_rad, const int* __restrict__ rank_ang,
    uint4* __restrict__ rad_pay, uint4* __restrict__ ang_rec,
    int n_edges, int n_pairs, int nb_rad)
{
    int bid = blockIdx.x;
    int t = threadIdx.x;
    if (bid < nb_rad) {
        int i = bid * 256 + t;
        if (i >= n_edges) return;
        float d  = dist[i];
        float ps = 0.25f * sw[i];
        float4 v = val_atom[edst[i]];
        uint4 rec;
        rec.x = __float_as_uint(d);
        rec.y = pack2(ps * v.x, ps * v.y);
        rec.z = pack2(ps * v.z, ps * v.w);
        rec.w = 0u;
        int slot = rad_offsets[esrc[i]] + rank_rad[i];
        rad_pay[slot] = rec;
    } else {
        int p = (bid - nb_rad) * 256 + t;
        if (p >= n_pairs) return;
        uint4 rec;
        rec.x = (unsigned)psrc[p];
        rec.y = (unsigned)pdst[p];
        rec.z = __float_as_uint(ang_angles[p]);
        rec.w = 0u;
        int slot = ang_offsets[central[p]] + rank_ang[p];
        ang_rec[slot] = rec;
    }
}

// ============ phase B: one wave per atom ============
// waves [0, n_atoms): angular — coalesced slot records, edata gathers, MFMA
// waves [n_atoms, 2n): radial broadcast-gather + onehot
__global__ __launch_bounds__(256) void phaseB_kernel(
    const uint4* __restrict__ ang_rec, const int* __restrict__ ang_offsets,
    const uint4* __restrict__ edata,
    const uint4* __restrict__ rad_pay, const int* __restrict__ rad_offsets,
    const int* __restrict__ species,
    float* __restrict__ out, int n_atoms)
{
    __shared__ uint4 sh[4][256];      // 4KB per wave, wave-private
    int wid  = (blockIdx.x << 2) + (threadIdx.x >> 6);
    int lane = threadIdx.x & 63;
    uint4* my = sh[threadIdx.x >> 6];

    if (wid < n_atoms) {
        // ---------------- angular (MFMA) ----------------
        int atom = wid;
        int beg = ang_offsets[atom];
        int end = ang_offsets[atom + 1];
        int m  = lane & 15;          // MFMA row (az) for A / col (ij) for B
        int g4 = lane >> 4;          // k-group
        const _Float16* hl = (const _Float16*)my;   // pair-major: 32 halves/pair
        f32x4 acc = {0.f, 0.f, 0.f, 0.f};

        for (int base = beg; base < end; base += 64) {
            int idx = base + lane;
            unsigned q[16];
            if (idx < end) {
                uint4 pr = ang_rec[idx];            // coalesced 16B
                int e1 = (int)pr.x;
                int e2 = (int)pr.y;
                float ang = __uint_as_float(pr.z);
                uint4 r1 = edata[e1];               // 2 cache-hot gathers
                uint4 r2 = edata[e2];
                float d12 = 0.5f * (__uint_as_float(r1.x) + __uint_as_float(r2.x));
                float swp = 2.0f * __uint_as_float(r1.y) * __uint_as_float(r2.y);
                float2 v1a = unpack2(r1.z), v1b = unpack2(r1.w);
                float2 v2a = unpack2(r2.z), v2b = unpack2(r2.w);
                float vp[4] = {v1a.x + v2a.x, v1a.y + v2a.y, v1b.x + v2b.x, v1b.y + v2b.y};
                float vm[4] = {v1a.x * v2a.x, v1a.y * v2a.y, v1b.x * v2b.x, v1b.y * v2b.y};

                float sa, ca;
                __sincosf(ang, &sa, &ca);
                const float czv[4] = { 0.92387953f,  0.38268343f, -0.38268343f, -0.92387953f };
                const float szv[4] = { 0.38268343f,  0.92387953f,  0.92387953f,  0.38268343f };
                float f1v[4];
                #pragma unroll
                for (int z = 0; z < 4; ++z) {
                    float y = 0.5f + 0.5f * (ca * czv[z] + sa * szv[z]);
                    float y2 = y * y, y4 = y2 * y2, y8 = y4 * y4, y16 = y8 * y8;
                    f1v[z] = y16 * y16;             // y^32
                }
                float f2sv[4];
                #pragma unroll
                for (int a = 0; a < 4; ++a) {
                    float x = d12 - (0.8f + 0.675f * (float)a);
                    f2sv[a] = swp * __expf(-8.0f * x * x);
                }
                #pragma unroll
                for (int a = 0; a < 4; ++a) {       // w[az] = f2s[a]*f1[z]
                    q[a * 2 + 0] = pack2(f2sv[a] * f1v[0], f2sv[a] * f1v[1]);
                    q[a * 2 + 1] = pack2(f2sv[a] * f1v[2], f2sv[a] * f1v[3]);
                }
                #pragma unroll
                for (int i2 = 0; i2 < 4; ++i2) {    // u[ij] = vp[i]*vm[j]
                    q[8 + i2 * 2 + 0] = pack2(vp[i2] * vm[0], vp[i2] * vm[1]);
                    q[8 + i2 * 2 + 1] = pack2(vp[i2] * vm[2], vp[i2] * vm[3]);
                }
            } else {
                #pragma unroll
                for (int k = 0; k < 16; ++k) q[k] = 0u;   // zero-pad tail pairs
            }
            // stage pair record: [w0..15 | u0..15] halves at 64B stride
            my[lane * 4 + 0] = make_uint4(q[0],  q[1],  q[2],  q[3]);
            my[lane * 4 + 1] = make_uint4(q[4],  q[5],  q[6],  q[7]);
            my[lane * 4 + 2] = make_uint4(q[8],  q[9],  q[10], q[11]);
            my[lane * 4 + 3] = make_uint4(q[12], q[13], q[14], q[15]);
            asm volatile("s_waitcnt lgkmcnt(0)" ::: "memory");

            int cnt = min(64, end - base);
            {
                f16x8 wf, uf;
                #pragma unroll
                for (int i = 0; i < 8; ++i) {
                    int row = (g4 << 3) + i;        // pairs 0..31
                    wf[i] = hl[row * 32 + m];
                    uf[i] = hl[row * 32 + 16 + m];
                }
                acc = __builtin_amdgcn_mfma_f32_16x16x32_f16(wf, uf, acc, 0, 0, 0);
            }
            if (cnt > 32) {
                f16x8 wf, uf;
                #pragma unroll
                for (int i = 0; i < 8; ++i) {
                    int row = 32 + (g4 << 3) + i;   // pairs 32..63
                    wf[i] = hl[row * 32 + m];
                    uf[i] = hl[row * 32 + 16 + m];
                }
                acc = __builtin_amdgcn_mfma_f32_16x16x32_f16(wf, uf, acc, 0, 0, 0);
            }
            asm volatile("s_waitcnt lgkmcnt(0)" ::: "memory");
        }
        // C/D layout (m89-verified): col = lane&15, row = (lane>>4)*4 + reg
        float* orow = out + (size_t)atom * NCOLS + ANG_OFF;
        #pragma unroll
        for (int r = 0; r < 4; ++r)
            orow[(g4 * 4 + r) * 16 + m] = acc[r];
        return;
    }

    // ---------------- radial + onehot ----------------
    int atom = wid - n_atoms;
    if (atom >= n_atoms) return;
    int beg = rad_offsets[atom];
    int end = rad_offsets[atom + 1];
    int r = lane >> 2, k = lane & 3;
    float shift = 0.8f + 0.275f * (float)r;
    float acc = 0.0f;
    for (int base = beg; base < end; base += 64) {
        int idx = base + lane;
        if (idx < end) my[lane] = rad_pay[idx];     // coalesced 16B
        asm volatile("s_waitcnt lgkmcnt(0)" ::: "memory");
        int cnt = min(64, end - base);
        for (int e = 0; e < cnt; ++e) {
            uint4 rec = my[e];                      // broadcast b128
            float d = __uint_as_float(rec.x);
            float2 f01 = unpack2(rec.y);
            float2 f23 = unpack2(rec.z);
            float pv = (k == 0) ? f01.x : (k == 1) ? f01.y : (k == 2) ? f23.x : f23.y;
            float x = d - shift;
            acc += __expf(-16.0f * x * x) * pv;
        }
        asm volatile("s_waitcnt lgkmcnt(0)" ::: "memory");
    }
    size_t rowbase = (size_t)atom * NCOLS;
    out[rowbase + RAD_OFF + lane] = acc;
    int sp = species[atom];
    out[rowbase + lane] = (lane == sp) ? 1.0f : 0.0f;
    if (lane < 23) out[rowbase + 64 + lane] = ((64 + lane) == sp) ? 1.0f : 0.0f;
}

extern "C" void kernel_launch(void* const* d_in, const int* in_sizes, int n_in,
                              void* d_out, int out_size, void* d_ws, size_t ws_size,
                              hipStream_t stream) {
    const int*   species      = (const int*)  d_in[0];
    const float* distances    = (const float*)d_in[1];
    const float* switch_      = (const float*)d_in[2];
    const int*   edge_src     = (const int*)  d_in[3];
    const int*   edge_dst     = (const int*)  d_in[4];
    const float* ang_angles   = (const float*)d_in[5];
    const float* ang_dist     = (const float*)d_in[6];
    const float* ang_switch   = (const float*)d_in[7];
    const int*   ang_edge_dst = (const int*)  d_in[8];
    const int*   angle_src    = (const int*)  d_in[9];
    const int*   angle_dst    = (const int*)  d_in[10];
    const int*   central_atom = (const int*)  d_in[11];
    const float4* valence     = (const float4*)d_in[12];

    float* out = (float*)d_out;

    const int n_atoms     = in_sizes[0];
    const int n_edges     = in_sizes[1];
    const int n_ang_edges = in_sizes[6];
    const int n_pairs     = in_sizes[5];

    // ---- workspace layout (16B-aligned), total ~= 27.3 MB ----
    char* ws = (char*)d_ws;
    size_t off = 0;
    auto alloc = [&](size_t bytes) -> void* {
        void* p = ws + off;
        off = (off + bytes + 15) & ~(size_t)15;
        return p;
    };
    uint4*  rad_pay     = (uint4*) alloc((size_t)n_edges * 16);                 // 10.24 MB
    uint4*  ang_rec     = (uint4*) alloc((size_t)n_pairs * 16);                 //  8.96 MB
    uint4*  edata       = (uint4*) alloc((size_t)n_ang_edges * 16);             //  2.56 MB
    int*    rank_rad    = (int*)   alloc((size_t)n_edges * sizeof(int));        //  2.56 MB
    int*    rank_ang    = (int*)   alloc((size_t)n_pairs * sizeof(int));        //  2.24 MB
    float4* val_atom    = (float4*)alloc((size_t)n_atoms * sizeof(float4));     //  0.32 MB
    int*    counts      = (int*)   alloc((size_t)2 * n_atoms * sizeof(int));    //  0.16 MB
    int*    rad_offsets = (int*)   alloc((size_t)(n_atoms + 1) * sizeof(int));
    int*    ang_offsets = (int*)   alloc((size_t)(n_atoms + 1) * sizeof(int));
    int* rad_counts = counts;
    int* ang_counts = counts + n_atoms;

    init_kernel<<<(2 * n_atoms + 255) / 256, 256, 0, stream>>>(
        species, valence, val_atom, counts, n_atoms);

    int n_work = n_edges + n_pairs;
    hist_kernel<<<(n_work + 255) / 256, 256, 0, stream>>>(
        edge_src, central_atom, ang_dist, ang_switch, ang_edge_dst, val_atom,
        rad_counts, ang_counts, rank_rad, rank_ang, edata,
        n_edges, n_pairs, n_ang_edges);

    scan_kernel<<<2, 1024, 0, stream>>>(rad_counts, ang_counts, rad_offsets, ang_offsets, n_atoms);

    int nb_rad = (n_edges + 255) / 256;
    int nb_ang = (n_pairs + 255) / 256;
    scatter_kernel<<<nb_rad + nb_ang, 256, 0, stream>>>(
        distances, switch_, edge_src, edge_dst,
        ang_angles, angle_src, angle_dst, central_atom,
        val_atom, rad_offsets, ang_offsets, rank_rad, rank_ang,
        rad_pay, ang_rec, n_edges, n_pairs, nb_rad);

    int nb_B = (2 * n_atoms + 3) / 4;    // 4 waves/block, 1 atom per wave
    phaseB_kernel<<<nb_B, 256, 0, stream>>>(
        ang_rec, ang_offsets, edata, rad_pay, rad_offsets, species, out, n_atoms);
}

// Round 9
// 123.552 us; speedup vs baseline: 1.7455x; 1.1527x over previous
//
#include <hip/hip_runtime.h>
#include <hip/hip_fp16.h>
#include <math.h>

// ---- problem constants (match reference) ----
#define NCOLS   407
#define RAD_OFF 87
#define ANG_OFF 151
#define NBINS   20000   // n_atoms LDS-histogram capacity (78.1 KiB -> 2 blocks/CU)
#define NBH     128     // histogram blocks per graph

// shiftR[r] = 0.8 + r*0.275  (r=0..15)
// shiftA[a] = 0.8 + a*0.675  (a=0..3)
// shiftZ[z] = pi/8 + z*pi/4  (z=0..3)

typedef __attribute__((ext_vector_type(8))) _Float16 f16x8;
typedef __attribute__((ext_vector_type(4))) float    f32x4;

static __device__ inline unsigned pack2(float a, float b) {
    __half2 h = __floats2half2_rn(a, b);
    return *reinterpret_cast<unsigned*>(&h);
}
static __device__ inline float2 unpack2(unsigned u) {
    __half2 h = *reinterpret_cast<__half2*>(&u);
    return __half22float2(h);
}

// ============ init: per-atom valence table ============
__global__ __launch_bounds__(256) void init_kernel(const int* __restrict__ species,
                                                   const float4* __restrict__ valence,
                                                   float4* __restrict__ val_atom,
                                                   int n_atoms) {
    int idx = blockIdx.x * 256 + threadIdx.x;
    if (idx < n_atoms) val_atom[idx] = valence[species[idx]];
}

// ============ A: per-block LDS histogram (NO global atomics) + edata build ============
// blocks [0,NBH): radial chunks; [NBH,2NBH): angular chunks; rest: edata
// edata[e] = { f32 d, f32 sw, half2 v01, half2 v23 }  (16B)
__global__ __launch_bounds__(256) void histA_kernel(const int* __restrict__ esrc,
                                                    const int* __restrict__ central,
                                                    const float* __restrict__ ang_dist,
                                                    const float* __restrict__ ang_sw,
                                                    const int* __restrict__ ang_edge_dst,
                                                    const float4* __restrict__ val_atom,
                                                    int* __restrict__ histG,
                                                    uint4* __restrict__ edata,
                                                    int n_edges, int n_pairs, int n_ang_edges,
                                                    int n_atoms, int ch_rad, int ch_ang) {
    __shared__ int lh[NBINS];
    int bid = blockIdx.x;
    int t = threadIdx.x;

    if (bid < 2 * NBH) {
        int is_ang = bid >= NBH;
        int b = is_ang ? bid - NBH : bid;
        const int* key = is_ang ? central : esrc;
        int n  = is_ang ? n_pairs : n_edges;
        int ch = is_ang ? ch_ang : ch_rad;
        for (int i = t; i < n_atoms; i += 256) lh[i] = 0;
        __syncthreads();
        int lo = b * ch, hi = min(lo + ch, n);
        for (int i = lo + t; i < hi; i += 256)
            atomicAdd(&lh[key[i]], 1);                  // LDS atomic: cheap
        __syncthreads();
        int* row = histG + (size_t)bid * n_atoms;
        for (int i = t; i < n_atoms; i += 256) row[i] = lh[i];   // coalesced dump
        return;
    }

    // ---- edata blocks: 2560 edges each ----
    int i = (bid - 2 * NBH) * 2560 + t;
    #pragma unroll
    for (int k = 0; k < 10; ++k, i += 256) {
        if (i < n_ang_edges) {
            float4 v = val_atom[ang_edge_dst[i]];
            uint4 r;
            r.x = __float_as_uint(ang_dist[i]);
            r.y = __float_as_uint(ang_sw[i]);
            r.z = pack2(v.x, v.y);
            r.w = pack2(v.z, v.w);
            edata[i] = r;
        }
    }
}

// ============ B1: per-atom totals = column sum of histG (coalesced) ============
__global__ __launch_bounds__(256) void totals_kernel(const int* __restrict__ histG,
                                                     int* __restrict__ counts,
                                                     int n_atoms) {
    int g = blockIdx.x * 256 + threadIdx.x;
    if (g >= 2 * n_atoms) return;
    int graph = g / n_atoms;
    int bin = g - graph * n_atoms;
    const int* base = histG + (size_t)(graph * NBH) * n_atoms + bin;
    int s = 0;
    for (int b = 0; b < NBH; ++b) s += base[(size_t)b * n_atoms];
    counts[g] = s;
}

// ============ B2: fused scan: block 0 = radial, block 1 = angular ============
__global__ __launch_bounds__(1024) void scan_kernel(const int* __restrict__ rad_counts,
                                                    const int* __restrict__ ang_counts,
                                                    int* __restrict__ rad_offsets,
                                                    int* __restrict__ ang_offsets,
                                                    int n) {
    const int* counts = (blockIdx.x == 0) ? rad_counts  : ang_counts;
    int* offsets      = (blockIdx.x == 0) ? rad_offsets : ang_offsets;
    __shared__ int part[1024];
    int t = threadIdx.x;
    int C = (n + 1023) >> 10;
    int lo = min(t * C, n);
    int hi = min(lo + C, n);
    int s = 0;
    for (int i = lo; i < hi; ++i) s += counts[i];
    part[t] = s;
    __syncthreads();
    for (int off = 1; off < 1024; off <<= 1) {
        int v = (t >= off) ? part[t - off] : 0;
        __syncthreads();
        part[t] += v;
        __syncthreads();
    }
    int run = part[t] - s;   // exclusive base
    for (int i = lo; i < hi; ++i) {
        int c = counts[i];
        offsets[i] = run;
        run += c;
    }
    if (t == 1023) offsets[n] = part[1023];
}

// ============ B3: histG[b][bin] <- offsets[bin] + prefix_{b'<b} (in place) ============
__global__ __launch_bounds__(256) void blockoffs_kernel(int* __restrict__ histG,
                                                        const int* __restrict__ rad_offsets,
                                                        const int* __restrict__ ang_offsets,
                                                        int n_atoms) {
    int g = blockIdx.x * 256 + threadIdx.x;
    if (g >= 2 * n_atoms) return;
    int graph = g / n_atoms;
    int bin = g - graph * n_atoms;
    int run = graph ? ang_offsets[bin] : rad_offsets[bin];
    int* base = histG + (size_t)(graph * NBH) * n_atoms + bin;
    for (int b = 0; b < NBH; ++b) {
        int tmp = base[(size_t)b * n_atoms];
        base[(size_t)b * n_atoms] = run;
        run += tmp;
    }
}

// ============ C: slot assign via LDS returned-atomic + payload store ============
// radial : 16B record {d, pv01, pv23, 0} to slot
// angular: 16B record {e1, e2, angle_bits, 0} to slot
__global__ __launch_bounds__(256) void scatterC_kernel(
    const float* __restrict__ dist, const float* __restrict__ sw,
    const int* __restrict__ esrc, const int* __restrict__ edst,
    const float* __restrict__ ang_angles,
    const int* __restrict__ psrc, const int* __restrict__ pdst,
    const int* __restrict__ central,
    const float4* __restrict__ val_atom,
    const int* __restrict__ histG,
    uint4* __restrict__ rad_pay, uint4* __restrict__ ang_rec,
    int n_edges, int n_pairs, int n_atoms, int ch_rad, int ch_ang)
{
    __shared__ int lh[NBINS];
    int bid = blockIdx.x;
    int t = threadIdx.x;
    int is_ang = bid >= NBH;
    int b = is_ang ? bid - NBH : bid;

    const int* row = histG + (size_t)bid * n_atoms;    // same row A wrote, B3 rewrote
    for (int i = t; i < n_atoms; i += 256) lh[i] = row[i];
    __syncthreads();

    if (!is_ang) {
        int lo = b * ch_rad, hi = min(lo + ch_rad, n_edges);
        for (int i = lo + t; i < hi; i += 256) {
            float d  = dist[i];
            float ps = 0.25f * sw[i];
            float4 v = val_atom[edst[i]];
            uint4 rec;
            rec.x = __float_as_uint(d);
            rec.y = pack2(ps * v.x, ps * v.y);
            rec.z = pack2(ps * v.z, ps * v.w);
            rec.w = 0u;
            int slot = atomicAdd(&lh[esrc[i]], 1);     // LDS returned atomic
            rad_pay[slot] = rec;
        }
    } else {
        int lo = b * ch_ang, hi = min(lo + ch_ang, n_pairs);
        for (int p = lo + t; p < hi; p += 256) {
            uint4 rec;
            rec.x = (unsigned)psrc[p];
            rec.y = (unsigned)pdst[p];
            rec.z = __float_as_uint(ang_angles[p]);
            rec.w = 0u;
            int slot = atomicAdd(&lh[central[p]], 1);
            ang_rec[slot] = rec;
        }
    }
}

// ============ phase B: one wave per atom ============
// waves [0, n_atoms): angular — coalesced slot records, edata gathers, MFMA
// waves [n_atoms, 2n): radial broadcast-gather + onehot
__global__ __launch_bounds__(256) void phaseB_kernel(
    const uint4* __restrict__ ang_rec, const int* __restrict__ ang_offsets,
    const uint4* __restrict__ edata,
    const uint4* __restrict__ rad_pay, const int* __restrict__ rad_offsets,
    const int* __restrict__ species,
    float* __restrict__ out, int n_atoms)
{
    __shared__ uint4 sh[4][256];      // 4KB per wave, wave-private
    int wid  = (blockIdx.x << 2) + (threadIdx.x >> 6);
    int lane = threadIdx.x & 63;
    uint4* my = sh[threadIdx.x >> 6];

    if (wid < n_atoms) {
        // ---------------- angular (MFMA) ----------------
        int atom = wid;
        int beg = ang_offsets[atom];
        int end = ang_offsets[atom + 1];
        int m  = lane & 15;          // MFMA row (az) for A / col (ij) for B
        int g4 = lane >> 4;          // k-group
        const _Float16* hl = (const _Float16*)my;   // pair-major: 32 halves/pair
        f32x4 acc = {0.f, 0.f, 0.f, 0.f};

        for (int base = beg; base < end; base += 64) {
            int idx = base + lane;
            unsigned q[16];
            if (idx < end) {
                uint4 pr = ang_rec[idx];            // coalesced 16B
                int e1 = (int)pr.x;
                int e2 = (int)pr.y;
                float ang = __uint_as_float(pr.z);
                uint4 r1 = edata[e1];               // 2 cache-hot gathers
                uint4 r2 = edata[e2];
                float d12 = 0.5f * (__uint_as_float(r1.x) + __uint_as_float(r2.x));
                float swp = 2.0f * __uint_as_float(r1.y) * __uint_as_float(r2.y);
                float2 v1a = unpack2(r1.z), v1b = unpack2(r1.w);
                float2 v2a = unpack2(r2.z), v2b = unpack2(r2.w);
                float vp[4] = {v1a.x + v2a.x, v1a.y + v2a.y, v1b.x + v2b.x, v1b.y + v2b.y};
                float vm[4] = {v1a.x * v2a.x, v1a.y * v2a.y, v1b.x * v2b.x, v1b.y * v2b.y};

                float sa, ca;
                __sincosf(ang, &sa, &ca);
                const float czv[4] = { 0.92387953f,  0.38268343f, -0.38268343f, -0.92387953f };
                const float szv[4] = { 0.38268343f,  0.92387953f,  0.92387953f,  0.38268343f };
                float f1v[4];
                #pragma unroll
                for (int z = 0; z < 4; ++z) {
                    float y = 0.5f + 0.5f * (ca * czv[z] + sa * szv[z]);
                    float y2 = y * y, y4 = y2 * y2, y8 = y4 * y4, y16 = y8 * y8;
                    f1v[z] = y16 * y16;             // y^32
                }
                float f2sv[4];
                #pragma unroll
                for (int a = 0; a < 4; ++a) {
                    float x = d12 - (0.8f + 0.675f * (float)a);
                    f2sv[a] = swp * __expf(-8.0f * x * x);
                }
                #pragma unroll
                for (int a = 0; a < 4; ++a) {       // w[az] = f2s[a]*f1[z]
                    q[a * 2 + 0] = pack2(f2sv[a] * f1v[0], f2sv[a] * f1v[1]);
                    q[a * 2 + 1] = pack2(f2sv[a] * f1v[2], f2sv[a] * f1v[3]);
                }
                #pragma unroll
                for (int i2 = 0; i2 < 4; ++i2) {    // u[ij] = vp[i]*vm[j]
                    q[8 + i2 * 2 + 0] = pack2(vp[i2] * vm[0], vp[i2] * vm[1]);
                    q[8 + i2 * 2 + 1] = pack2(vp[i2] * vm[2], vp[i2] * vm[3]);
                }
            } else {
                #pragma unroll
                for (int k = 0; k < 16; ++k) q[k] = 0u;   // zero-pad tail pairs
            }
            // stage pair record: [w0..15 | u0..15] halves at 64B stride
            my[lane * 4 + 0] = make_uint4(q[0],  q[1],  q[2],  q[3]);
            my[lane * 4 + 1] = make_uint4(q[4],  q[5],  q[6],  q[7]);
            my[lane * 4 + 2] = make_uint4(q[8],  q[9],  q[10], q[11]);
            my[lane * 4 + 3] = make_uint4(q[12], q[13], q[14], q[15]);
            asm volatile("s_waitcnt lgkmcnt(0)" ::: "memory");

            int cnt = min(64, end - base);
            {
                f16x8 wf, uf;
                #pragma unroll
                for (int i = 0; i < 8; ++i) {
                    int row = (g4 << 3) + i;        // pairs 0..31
                    wf[i] = hl[row * 32 + m];
                    uf[i] = hl[row * 32 + 16 + m];
                }
                acc = __builtin_amdgcn_mfma_f32_16x16x32_f16(wf, uf, acc, 0, 0, 0);
            }
            if (cnt > 32) {
                f16x8 wf, uf;
                #pragma unroll
                for (int i = 0; i < 8; ++i) {
                    int row = 32 + (g4 << 3) + i;   // pairs 32..63
                    wf[i] = hl[row * 32 + m];
                    uf[i] = hl[row * 32 + 16 + m];
                }
                acc = __builtin_amdgcn_mfma_f32_16x16x32_f16(wf, uf, acc, 0, 0, 0);
            }
            asm volatile("s_waitcnt lgkmcnt(0)" ::: "memory");
        }
        // C/D layout (m89-verified): col = lane&15, row = (lane>>4)*4 + reg
        float* orow = out + (size_t)atom * NCOLS + ANG_OFF;
        #pragma unroll
        for (int r = 0; r < 4; ++r)
            orow[(g4 * 4 + r) * 16 + m] = acc[r];
        return;
    }

    // ---------------- radial + onehot ----------------
    int atom = wid - n_atoms;
    if (atom >= n_atoms) return;
    int beg = rad_offsets[atom];
    int end = rad_offsets[atom + 1];
    int r = lane >> 2, k = lane & 3;
    float shift = 0.8f + 0.275f * (float)r;
    float acc = 0.0f;
    for (int base = beg; base < end; base += 64) {
        int idx = base + lane;
        if (idx < end) my[lane] = rad_pay[idx];     // coalesced 16B
        asm volatile("s_waitcnt lgkmcnt(0)" ::: "memory");
        int cnt = min(64, end - base);
        for (int e = 0; e < cnt; ++e) {
            uint4 rec = my[e];                      // broadcast b128
            float d = __uint_as_float(rec.x);
            float2 f01 = unpack2(rec.y);
            float2 f23 = unpack2(rec.z);
            float pv = (k == 0) ? f01.x : (k == 1) ? f01.y : (k == 2) ? f23.x : f23.y;
            float x = d - shift;
            acc += __expf(-16.0f * x * x) * pv;
        }
        asm volatile("s_waitcnt lgkmcnt(0)" ::: "memory");
    }
    size_t rowbase = (size_t)atom * NCOLS;
    out[rowbase + RAD_OFF + lane] = acc;
    int sp = species[atom];
    out[rowbase + lane] = (lane == sp) ? 1.0f : 0.0f;
    if (lane < 23) out[rowbase + 64 + lane] = ((64 + lane) == sp) ? 1.0f : 0.0f;
}

extern "C" void kernel_launch(void* const* d_in, const int* in_sizes, int n_in,
                              void* d_out, int out_size, void* d_ws, size_t ws_size,
                              hipStream_t stream) {
    const int*   species      = (const int*)  d_in[0];
    const float* distances    = (const float*)d_in[1];
    const float* switch_      = (const float*)d_in[2];
    const int*   edge_src     = (const int*)  d_in[3];
    const int*   edge_dst     = (const int*)  d_in[4];
    const float* ang_angles   = (const float*)d_in[5];
    const float* ang_dist     = (const float*)d_in[6];
    const float* ang_switch   = (const float*)d_in[7];
    const int*   ang_edge_dst = (const int*)  d_in[8];
    const int*   angle_src    = (const int*)  d_in[9];
    const int*   angle_dst    = (const int*)  d_in[10];
    const int*   central_atom = (const int*)  d_in[11];
    const float4* valence     = (const float4*)d_in[12];

    float* out = (float*)d_out;

    const int n_atoms     = in_sizes[0];
    const int n_edges     = in_sizes[1];
    const int n_ang_edges = in_sizes[6];
    const int n_pairs     = in_sizes[5];

    // ---- workspace layout (16B-aligned), total ~= 42.9 MB ----
    char* ws = (char*)d_ws;
    size_t off = 0;
    auto alloc = [&](size_t bytes) -> void* {
        void* p = ws + off;
        off = (off + bytes + 15) & ~(size_t)15;
        return p;
    };
    int*    histG       = (int*)   alloc((size_t)2 * NBH * n_atoms * sizeof(int)); // 20.48 MB
    uint4*  rad_pay     = (uint4*) alloc((size_t)n_edges * 16);                    // 10.24 MB
    uint4*  ang_rec     = (uint4*) alloc((size_t)n_pairs * 16);                    //  8.96 MB
    uint4*  edata       = (uint4*) alloc((size_t)n_ang_edges * 16);                //  2.56 MB
    float4* val_atom    = (float4*)alloc((size_t)n_atoms * sizeof(float4));        //  0.32 MB
    int*    counts      = (int*)   alloc((size_t)2 * n_atoms * sizeof(int));       //  0.16 MB
    int*    rad_offsets = (int*)   alloc((size_t)(n_atoms + 1) * sizeof(int));
    int*    ang_offsets = (int*)   alloc((size_t)(n_atoms + 1) * sizeof(int));
    int* rad_counts = counts;
    int* ang_counts = counts + n_atoms;

    int ch_rad = (n_edges + NBH - 1) / NBH;
    int ch_ang = (n_pairs + NBH - 1) / NBH;

    init_kernel<<<(n_atoms + 255) / 256, 256, 0, stream>>>(
        species, valence, val_atom, n_atoms);

    int nb_edata = (n_ang_edges + 2559) / 2560;
    histA_kernel<<<2 * NBH + nb_edata, 256, 0, stream>>>(
        edge_src, central_atom, ang_dist, ang_switch, ang_edge_dst, val_atom,
        histG, edata, n_edges, n_pairs, n_ang_edges, n_atoms, ch_rad, ch_ang);

    totals_kernel<<<(2 * n_atoms + 255) / 256, 256, 0, stream>>>(histG, counts, n_atoms);

    scan_kernel<<<2, 1024, 0, stream>>>(rad_counts, ang_counts, rad_offsets, ang_offsets, n_atoms);

    blockoffs_kernel<<<(2 * n_atoms + 255) / 256, 256, 0, stream>>>(
        histG, rad_offsets, ang_offsets, n_atoms);

    scatterC_kernel<<<2 * NBH, 256, 0, stream>>>(
        distances, switch_, edge_src, edge_dst,
        ang_angles, angle_src, angle_dst, central_atom,
        val_atom, histG, rad_pay, ang_rec,
        n_edges, n_pairs, n_atoms, ch_rad, ch_ang);

    int nb_B = (2 * n_atoms + 3) / 4;    // 4 waves/block, 1 atom per wave
    phaseB_kernel<<<nb_B, 256, 0, stream>>>(
        ang_rec, ang_offsets, edata, rad_pay, rad_offsets, species, out, n_atoms);
}